// Round 7
// baseline (324.370 us; speedup 1.0000x reference)
//
#include <hip/hip_runtime.h>
#include <hip/hip_bf16.h>
#include <cstdint>
#include <cstddef>

#define B_ 4
#define L_ 2048
#define C_ 1024
#define H_ 16
#define D_ 64

typedef __bf16    bf16x2 __attribute__((ext_vector_type(2)));
typedef __bf16    bf16x4 __attribute__((ext_vector_type(4)));
typedef __bf16    bf16x8 __attribute__((ext_vector_type(8)));
typedef _Float16  f16x4  __attribute__((ext_vector_type(4)));
typedef _Float16  f16x8  __attribute__((ext_vector_type(8)));
typedef float     f32x4  __attribute__((ext_vector_type(4)));

// async global->LDS, 16 B per lane. LDS dest = wave-uniform base + lane*16.
typedef const __attribute__((address_space(1))) uint32_t* gas_ptr;
typedef __attribute__((address_space(3))) uint32_t* las_ptr;
__device__ __forceinline__ void gl_lds16(const void* g, void* l) {
    __builtin_amdgcn_global_load_lds((gas_ptr)(uintptr_t)g,
                                     (las_ptr)(uintptr_t)l, 16, 0, 0);
}

// ---------------------------------------------------------------------------
// prep kernel: region A = x fp32->fp16 (8192 blocks), region B = Wqkv
// transpose+cvt (768 blocks), region C = Wout transpose+cvt (256 blocks).
// ---------------------------------------------------------------------------
__global__ __launch_bounds__(256) void prep_kernel(
    const float* __restrict__ x, _Float16* __restrict__ x16,
    const float* __restrict__ Wqkv, _Float16* __restrict__ Wq16,
    const float* __restrict__ Wout, _Float16* __restrict__ Wo16)
{
    __shared__ float tile[64][65];
    int bid = blockIdx.x;
    const int tid = threadIdx.x;

    if (bid < 8192) {                      // cvt x
        int i = (bid * 256 + tid) * 4;
        float4 v = *(const float4*)&x[i];
        f16x4 o = {(_Float16)v.x, (_Float16)v.y, (_Float16)v.z, (_Float16)v.w};
        *(f16x4*)&x16[i] = o;
        return;
    }
    bid -= 8192;
    const float* W; _Float16* Wt; int N, tx, ty;
    if (bid < 768) { W = Wqkv; Wt = Wq16; N = 3072; tx = bid % 48; ty = bid / 48; }
    else { bid -= 768; W = Wout; Wt = Wo16; N = 1024; tx = bid % 16; ty = bid / 16; }
    const int K = 1024;
    const int k0 = ty * 64, n0 = tx * 64;
    for (int i = tid; i < 1024; i += 256) {
        int r = i >> 4, c4 = (i & 15) * 4;
        float4 v = *(const float4*)&W[(size_t)(k0 + r) * N + n0 + c4];
        tile[r][c4 + 0] = v.x; tile[r][c4 + 1] = v.y;
        tile[r][c4 + 2] = v.z; tile[r][c4 + 3] = v.w;
    }
    __syncthreads();
    for (int i = tid; i < 1024; i += 256) {
        int n = i >> 4, k4 = (i & 15) * 4;
        f16x4 o = {(_Float16)tile[k4 + 0][n], (_Float16)tile[k4 + 1][n],
                   (_Float16)tile[k4 + 2][n], (_Float16)tile[k4 + 3][n]};
        *(f16x4*)&Wt[(size_t)(n0 + n) * K + k0 + k4] = o;
    }
}

// ---------------------------------------------------------------------------
// fp16 MFMA GEMM (m97 structure). MODE 0: proj (fp32 out + bias).
// MODE 1: QKV fused (bias + RMS norm on fp32 acc for q/k -> bf16 qkv;
//         v tiles: bias + bf16 + LDS transpose -> vT).
// ---------------------------------------------------------------------------
template <int MODE>
__global__ __launch_bounds__(256) void gemm_f16_bt_kernel(
    const _Float16* __restrict__ A, const _Float16* __restrict__ Bt,
    const float* __restrict__ bias, void* __restrict__ Cout,
    __bf16* __restrict__ vTout, const float* __restrict__ q_gamma,
    const float* __restrict__ k_gamma, int M, int N, int K)
{
    __shared__ __align__(16) char smraw[MODE == 1 ? 34816 : 16384];
    _Float16* Ash = (_Float16*)smraw;
    _Float16* Bsh = Ash + 128 * 32;

    const int tid  = threadIdx.x;
    const int lane = tid & 63;
    const int wv   = tid >> 6;
    const int wm   = wv & 1, wn = wv >> 1;
    const int n16  = lane & 15, quad = lane >> 4;
    const int brow = blockIdx.y * 128;
    const int bcol = blockIdx.x * 128;

    const int srow = lane >> 2;
    const int scol = (lane & 3) * 8;
    const _Float16* gA = A  + (size_t)(brow + wv * 32 + srow) * K + scol;
    const _Float16* gB = Bt + (size_t)(bcol + wv * 32 + srow) * K + scol;
    _Float16* lA0 = &Ash[wv * 1024];
    _Float16* lA1 = &Ash[wv * 1024 + 512];
    _Float16* lB0 = &Bsh[wv * 1024];
    _Float16* lB1 = &Bsh[wv * 1024 + 512];

    f32x4 acc[4][4] = {};

    for (int k0 = 0; k0 < K; k0 += 32) {
        gl_lds16(gA + k0,                  lA0);
        gl_lds16(gA + k0 + 16 * (size_t)K, lA1);
        gl_lds16(gB + k0,                  lB0);
        gl_lds16(gB + k0 + 16 * (size_t)K, lB1);
        __syncthreads();

        f16x8 ar[4], br[4];
        #pragma unroll
        for (int t = 0; t < 4; t++) {
            ar[t] = *(const f16x8*)&Ash[(wm * 64 + t * 16 + n16) * 32 + quad * 8];
            br[t] = *(const f16x8*)&Bsh[(wn * 64 + t * 16 + n16) * 32 + quad * 8];
        }
        #pragma unroll
        for (int i = 0; i < 4; i++)
            #pragma unroll
            for (int j = 0; j < 4; j++)
                acc[i][j] = __builtin_amdgcn_mfma_f32_16x16x32_f16(
                    ar[i], br[j], acc[i][j], 0, 0, 0);
        __syncthreads();
    }

    if (MODE == 0) {
        #pragma unroll
        for (int j = 0; j < 4; j++) {
            const int col = bcol + wn * 64 + j * 16 + n16;
            const float bv = bias[col];
            #pragma unroll
            for (int i = 0; i < 4; i++) {
                const int row0 = brow + wm * 64 + i * 16 + quad * 4;
                #pragma unroll
                for (int r = 0; r < 4; r++)
                    ((float*)Cout)[(size_t)(row0 + r) * N + col] = acc[i][j][r] + bv;
            }
        }
        return;
    }

    // ---------------- MODE 1: fused QKV epilogue ----------------
    const int region = bcol >> 10;         // 0 = q, 1 = k, 2 = v
    float bj[4];
    #pragma unroll
    for (int j = 0; j < 4; j++) bj[j] = bias[bcol + wn * 64 + j * 16 + n16];

    if (region < 2) {
        const float* gamma = (region == 0) ? q_gamma : k_gamma;
        const float scl = (region == 0) ? 1.44269504f : 8.0f;  // log2e | sqrt(D)
        const int cb = (bcol & 1023) + wn * 64 + n16;
        float gj[4];
        #pragma unroll
        for (int j = 0; j < 4; j++) gj[j] = gamma[cb + j * 16];

        #pragma unroll
        for (int i = 0; i < 4; i++) {
            #pragma unroll
            for (int r = 0; r < 4; r++) {
                float v0 = acc[i][0][r] + bj[0];
                float v1 = acc[i][1][r] + bj[1];
                float v2 = acc[i][2][r] + bj[2];
                float v3 = acc[i][3][r] + bj[3];
                float ss = v0 * v0 + v1 * v1 + v2 * v2 + v3 * v3;
                ss += __shfl_xor(ss, 1, 64);
                ss += __shfl_xor(ss, 2, 64);
                ss += __shfl_xor(ss, 4, 64);
                ss += __shfl_xor(ss, 8, 64);
                const float sc = scl / fmaxf(sqrtf(ss), 1e-12f);
                const int row = brow + wm * 64 + i * 16 + quad * 4 + r;
                __bf16* op = (__bf16*)Cout + (size_t)row * 3072 + bcol + wn * 64 + n16;
                op[ 0] = (__bf16)(v0 * gj[0] * sc);
                op[16] = (__bf16)(v1 * gj[1] * sc);
                op[32] = (__bf16)(v2 * gj[2] * sc);
                op[48] = (__bf16)(v3 * gj[3] * sc);
            }
        }
    } else {
        __syncthreads();
        __bf16* LT = (__bf16*)smraw;           // [col 0..127][row 0..127] s=136
        #pragma unroll
        for (int i = 0; i < 4; i++)
            #pragma unroll
            for (int j = 0; j < 4; j++) {
                const int col = wn * 64 + j * 16 + n16;
                const int row0 = wm * 64 + i * 16 + quad * 4;
                bf16x4 t4 = {(__bf16)(acc[i][j][0] + bj[j]),
                             (__bf16)(acc[i][j][1] + bj[j]),
                             (__bf16)(acc[i][j][2] + bj[j]),
                             (__bf16)(acc[i][j][3] + bj[j])};
                *(bf16x4*)&LT[col * 136 + row0] = t4;
            }
        __syncthreads();
        const int d = tid >> 1, hf = tid & 1;
        const int bidx = brow >> 11;
        const int l0 = (brow & 2047) + hf * 64;
        const int head = ((bcol - 2048) >> 6) + (d >> 6);
        const size_t vb = (((size_t)(bidx * 16 + head)) * 64 + (d & 63)) * 2048 + l0;
        #pragma unroll
        for (int u = 0; u < 8; u++)
            *(bf16x8*)&vTout[vb + u * 8] = *(const bf16x8*)&LT[d * 136 + hf * 64 + u * 8];
    }
}

// ---------------------------------------------------------------------------
// MFMA flash attention v4: Bq=128, no-max softmax, async swizzled staging.
//
// K/Vt tiles live UNPADDED [64][64] so staging uses global_load_lds w=16
// (4 instr/lane/tile, no VGPR round trip, no ds_writes). Bank conflicts
// avoided by XOR swizzle: LDS slot (row r, 8-elem block c) holds global
// block c ^ (r&7); frag reads fetch block b ^ (R&7) (b128 per block; 16
// lanes/quad -> 8 distinct block-groups x 2 = 2-way = free).
// Block index encodes bh in the low 6 bits so bid%8 = bh%8: all 16 q-tile
// blocks of one (b,h) land on the same XCD -> K/V stream stays in its L2.
// ---------------------------------------------------------------------------
__global__ __launch_bounds__(256) void attn_mfma_kernel(
    const __bf16* __restrict__ qkv, const __bf16* __restrict__ vT,
    _Float16* __restrict__ h16)
{
    const int tid  = threadIdx.x;
    const int lane = tid & 63;
    const int wv   = tid >> 6;
    const int n16  = lane & 15;
    const int quad = lane >> 4;
    const int bh = blockIdx.x & 63;        // XCD-locality: bid%8 == bh%8
    const int qt = blockIdx.x >> 6;
    const int bb = bh >> 4, hh = bh & 15;
    const int q0 = qt * 128;
    const int w32 = wv * 32;

    // QP [128][72] padded (Q then P) + Ksm/Vtm [64][64] unpadded swizzled
    __shared__ __align__(16) __bf16 smem[128 * 72 + 64 * 64 + 64 * 64];
    __bf16* QP  = smem;
    __bf16* Ksm = smem + 128 * 72;
    __bf16* Vtm = Ksm + 64 * 64;

    // ---- stage Q tile (pre-scaled by log2e in QKV epilogue) ----
    #pragma unroll
    for (int t = 0; t < 4; t++) {
        int i = tid + t * 256;
        int r = i >> 3, d8 = (i & 7) * 8;
        *(bf16x8*)&QP[r * 72 + d8] =
            *(const bf16x8*)&qkv[(size_t)(bb * L_ + q0 + r) * 3072 + hh * 64 + d8];
    }
    __syncthreads();

    bf16x8 qf[2][2];
    #pragma unroll
    for (int qg = 0; qg < 2; qg++)
        #pragma unroll
        for (int hf = 0; hf < 2; hf++)
            qf[qg][hf] = *(const bf16x8*)&QP[(w32 + qg * 16 + n16) * 72 + hf * 32 + quad * 8];
    __syncthreads();

    // ---- per-lane async-staging source pointers (swizzled) ----
    // call t covers LDS slots t*256 + wv*64 + lane; r = slot>>3, c = slot&7,
    // source block = c ^ (r&7)  (r&7 == lane>>3 here)
    const int sr = (wv << 3) + (lane >> 3);            // row/d 0..31 (+32)
    const int sc = ((lane & 7) ^ (lane >> 3)) * 8;     // swizzled col elems
    const __bf16* kp = &qkv[(size_t)(bb * L_ + sr) * 3072 + 1024 + hh * 64 + sc];
    const __bf16* vp = &vT[((size_t)bh * 64 + sr) * 2048 + sc];
    __bf16* kl0 = &Ksm[wv * 512];
    __bf16* kl1 = &Ksm[2048 + wv * 512];
    __bf16* vl0 = &Vtm[wv * 512];
    __bf16* vl1 = &Vtm[2048 + wv * 512];

    // frag-read swizzle offsets (row&7 == n16&7 for R = g*16 + n16)
    const int sw0 = ((quad ^ (n16 & 7)) << 3);
    const int sw1 = (((quad + 4) ^ (n16 & 7)) << 3);

    f32x4 O[2][4] = {};
    float l_run[2] = {0.f, 0.f};

    for (int j0 = 0; j0 < L_; j0 += 64) {
        gl_lds16(kp + (size_t)j0 * 3072,        kl0);
        gl_lds16(kp + (size_t)(j0 + 32) * 3072, kl1);
        gl_lds16(vp + j0,                        vl0);
        gl_lds16(vp + 32 * 2048 + j0,            vl1);
        __syncthreads();

        // ---- S^T = K @ Q^T ----
        f32x4 St[2][4] = {};
        #pragma unroll
        for (int kg = 0; kg < 4; kg++) {
            const int R = (kg * 16 + n16) * 64;
            bf16x8 a0 = *(const bf16x8*)&Ksm[R + sw0];
            bf16x8 a1 = *(const bf16x8*)&Ksm[R + sw1];
            St[0][kg] = __builtin_amdgcn_mfma_f32_16x16x32_bf16(a0, qf[0][0], St[0][kg], 0, 0, 0);
            St[0][kg] = __builtin_amdgcn_mfma_f32_16x16x32_bf16(a1, qf[0][1], St[0][kg], 0, 0, 0);
            St[1][kg] = __builtin_amdgcn_mfma_f32_16x16x32_bf16(a0, qf[1][0], St[1][kg], 0, 0, 0);
            St[1][kg] = __builtin_amdgcn_mfma_f32_16x16x32_bf16(a1, qf[1][1], St[1][kg], 0, 0, 0);
        }

        // ---- no-max softmax (|s_log2| <= 11.6 -> fp32-safe) ----
        #pragma unroll
        for (int qg = 0; qg < 2; qg++) {
            const int prow = (w32 + qg * 16 + n16) * 72;
            float ts = 0.f;
            #pragma unroll
            for (int kg = 0; kg < 4; kg++) {
                float p0 = __builtin_amdgcn_exp2f(St[qg][kg][0]);
                float p1 = __builtin_amdgcn_exp2f(St[qg][kg][1]);
                float p2 = __builtin_amdgcn_exp2f(St[qg][kg][2]);
                float p3 = __builtin_amdgcn_exp2f(St[qg][kg][3]);
                bf16x4 t4 = {(__bf16)p0, (__bf16)p1, (__bf16)p2, (__bf16)p3};
                *(bf16x4*)&QP[prow + kg * 16 + quad * 4] = t4;
                ts += (p0 + p1) + (p2 + p3);
            }
            ts += __shfl_xor(ts, 16, 64);
            ts += __shfl_xor(ts, 32, 64);
            l_run[qg] += ts;
        }

        // ---- O^T += V^T @ P^T ----
        bf16x8 pf[2][2];
        #pragma unroll
        for (int qg = 0; qg < 2; qg++)
            #pragma unroll
            for (int kh = 0; kh < 2; kh++)
                pf[qg][kh] = *(const bf16x8*)&QP[(w32 + qg * 16 + n16) * 72 + kh * 32 + quad * 8];

        #pragma unroll
        for (int dg = 0; dg < 4; dg++) {
            const int R = (dg * 16 + n16) * 64;
            bf16x8 v0 = *(const bf16x8*)&Vtm[R + sw0];
            bf16x8 v1 = *(const bf16x8*)&Vtm[R + sw1];
            O[0][dg] = __builtin_amdgcn_mfma_f32_16x16x32_bf16(v0, pf[0][0], O[0][dg], 0, 0, 0);
            O[0][dg] = __builtin_amdgcn_mfma_f32_16x16x32_bf16(v1, pf[0][1], O[0][dg], 0, 0, 0);
            O[1][dg] = __builtin_amdgcn_mfma_f32_16x16x32_bf16(v0, pf[1][0], O[1][dg], 0, 0, 0);
            O[1][dg] = __builtin_amdgcn_mfma_f32_16x16x32_bf16(v1, pf[1][1], O[1][dg], 0, 0, 0);
        }
        __syncthreads();
    }

    #pragma unroll
    for (int qg = 0; qg < 2; qg++) {
        const float linv = 1.0f / l_run[qg];
        const int q = q0 + w32 + qg * 16 + n16;
        const size_t orow = (size_t)(bb * L_ + q) * 1024 + hh * 64 + quad * 4;
        #pragma unroll
        for (int dg = 0; dg < 4; dg++) {
            f16x4 o = {(_Float16)(O[qg][dg][0] * linv),
                       (_Float16)(O[qg][dg][1] * linv),
                       (_Float16)(O[qg][dg][2] * linv),
                       (_Float16)(O[qg][dg][3] * linv)};
            *(f16x4*)&h16[orow + dg * 16] = o;
        }
    }
}

// ---------------------------------------------------------------------------
extern "C" void kernel_launch(void* const* d_in, const int* in_sizes, int n_in,
                              void* d_out, int out_size, void* d_ws, size_t ws_size,
                              hipStream_t stream)
{
    const float* x       = (const float*)d_in[0];
    const float* Wqkv    = (const float*)d_in[1];
    const float* bqkv    = (const float*)d_in[2];
    const float* q_gamma = (const float*)d_in[3];
    const float* k_gamma = (const float*)d_in[4];
    const float* Wout    = (const float*)d_in[5];
    const float* bout    = (const float*)d_in[6];
    float* out = (float*)d_out;

    uint8_t* ws = (uint8_t*)d_ws;
    _Float16* x16   = (_Float16*)(ws);                      // 16 MB
    _Float16* Wq16  = (_Float16*)(ws + (16ull << 20));      //  6 MB
    _Float16* Wo16  = (_Float16*)(ws + (22ull << 20));      //  2 MB
    __bf16*   qkv16 = (__bf16*)  (ws + (24ull << 20));      // 48 MB (q,k used)
    _Float16* h16   = (_Float16*)(ws + (72ull << 20));      // 16 MB
    __bf16*   vT    = (__bf16*)  (ws + (88ull << 20));      // 16 MB (total 104)

    // 1) prep: x->fp16, W transposes (one launch, 3 regions)
    prep_kernel<<<8192 + 768 + 256, 256, 0, stream>>>(x, x16, Wqkv, Wq16, Wout, Wo16);

    // 2) fused QKV: GEMM + bias + RMS-norm (q,k -> qkv16) + V transpose (-> vT)
    gemm_f16_bt_kernel<1><<<dim3(3 * C_ / 128, B_ * L_ / 128), 256, 0, stream>>>(
        x16, Wq16, bqkv, qkv16, vT, q_gamma, k_gamma, B_ * L_, 3 * C_, C_);

    // 3) flash attention (Bq=128, async swizzled staging, XCD-local) -> h16
    attn_mfma_kernel<<<B_ * H_ * (L_ / 128), 256, 0, stream>>>(qkv16, vT, h16);

    // 4) out = h @ Wout + bout -> fp32
    gemm_f16_bt_kernel<0><<<dim3(C_ / 128, B_ * L_ / 128), 256, 0, stream>>>(
        h16, Wo16, bout, out, nullptr, nullptr, nullptr, B_ * L_, C_, C_);
}